// Round 3
// baseline (616.459 us; speedup 1.0000x reference)
//
#include <hip/hip_runtime.h>

// ---------------------------------------------------------------------------
// GCN forward, reassociated: per layer h = relu( (A_hat h) W + b ).
// R15: concurrency + gather-issue rework of the fused layer.
//  - 16 rows per 1-wave block (grid 6256 = 24.4 blocks/CU avg; R14's 3128
//    blocks capped time-avg occupancy at ~9 waves/CU). LDS 4.3 KB.
//  - __launch_bounds__(64,8): force VGPR <= 64 so wave slots bind, not regs.
//  - gather loop: 8-edge batches, indices via two dwordx4 vector loads
//    (was 8 scalar broadcast loads), prefetched one batch ahead; remainder
//    folded into the masked batch (index clamped to self, weight 0) instead
//    of a serial per-edge latency chain. Packed f32x2 accumulate.
//  - ALL layers pre-scaled: fill_csr scales the bf16 x-cast by dinv in
//    place (histogram is already in LDS), so layer 1 = layers 2-4 path,
//    no per-edge dinv gather anywhere.
// Epilogue still folds bias+relu+output-dinv; layer 4 fuses the head dot.
// CSR build (binned, atomic-free hot path) unchanged. pairs aliases Hb1.
// NOTE: harness delivers integer inputs as int32 (edge_index/batch: int*).
// ---------------------------------------------------------------------------

constexpr int D = 128;
constexpr int NGRAPH = 512;
constexpr int CHUNK = 4096;       // edges per scatter block
constexpr int BSH = 9;            // 512 nodes per bucket
constexpr int OP = 136;           // out-tile pitch (ushorts): 272B, 16B-aligned rows

typedef __attribute__((ext_vector_type(8))) short bf16x8;
typedef __attribute__((ext_vector_type(4))) float f32x4;
typedef __attribute__((ext_vector_type(2))) float f32x2;
typedef int i32x4u __attribute__((ext_vector_type(4), aligned(4)));

__device__ __forceinline__ float bf2f(unsigned short b) {
    return __uint_as_float(((unsigned int)b) << 16);
}
__device__ __forceinline__ unsigned short f2bf(float f) {   // round-to-nearest-even
    unsigned int u = __float_as_uint(f);
    u += 0x7FFFu + ((u >> 16) & 1u);
    return (unsigned short)(u >> 16);
}
// unpack one dword holding 2 bf16 -> (lo, hi) as f32x2
__device__ __forceinline__ f32x2 unpk(unsigned int d) {
    f32x2 r;
    r.x = __uint_as_float(d << 16);
    r.y = __uint_as_float(d & 0xFFFF0000u);
    return r;
}

// merged independent setup: [0,CB) cast x->bf16 | [CB,CB+256) cast W ->
// transposed bf16 Wt | [CB+256, ...) per-chunk bucket histogram.
__global__ __launch_bounds__(256) void setup_all(
        const float4* __restrict__ x4, ushort4* __restrict__ hb, int n4, int CB,
        const float* __restrict__ W, unsigned short* __restrict__ Wt,
        const int* __restrict__ ec, int E, int* __restrict__ bucketCnt) {
    __shared__ int h[256];
    const int t = threadIdx.x;
    const int b = blockIdx.x;
    if (b < CB) {
        int i = b * 256 + t;
        if (i < n4) {
            float4 v = x4[i];
            ushort4 o;
            o.x = f2bf(v.x); o.y = f2bf(v.y); o.z = f2bf(v.z); o.w = f2bf(v.w);
            hb[i] = o;
        }
    } else if (b < CB + 256) {
        int idx = (b - CB) * 256 + t;      // 4*128*128 = 65536 elems
        int i = idx >> 14;
        int rem = idx & 16383;
        int k = rem >> 7, c = rem & 127;
        Wt[(i << 14) + c * 128 + k] = f2bf(W[idx]);
    } else {
        h[t] = 0;
        __syncthreads();
        const int e0 = (b - CB - 256) * CHUNK;
        const int cnt = min(CHUNK, E - e0);
        for (int i = t; i < cnt; i += 256) atomicAdd(&h[ec[e0 + i] >> BSH], 1);
        __syncthreads();
        if (h[t]) atomicAdd(&bucketCnt[t], h[t]);
    }
}

// exclusive scan over 256 bucket counts -> bucketBase, globCursor
__global__ __launch_bounds__(256) void bucket_scan(const int* __restrict__ bucketCnt,
                                                   int* __restrict__ bucketBase,
                                                   int* __restrict__ globCursor) {
    __shared__ int s[256];
    const int t = threadIdx.x;
    int v = bucketCnt[t];
    s[t] = v; __syncthreads();
    for (int off = 1; off < 256; off <<= 1) {
        int x = (t >= off) ? s[t - off] : 0;
        __syncthreads();
        s[t] += x;
        __syncthreads();
    }
    int excl = s[t] - v;
    bucketBase[t] = excl;
    globCursor[t] = excl;
}

// scatter (r,c) pairs into bucket-grouped array, LDS-staged & coalesced
__global__ __launch_bounds__(256) void scatter_pairs(const int* __restrict__ er,
                                                     const int* __restrict__ ec, int E,
                                                     int* __restrict__ globCursor,
                                                     int2* __restrict__ pairs) {
    __shared__ int h[256], lbase[256], cur[256], segd[256], s[256];
    __shared__ int2 stage[CHUNK];
    const int t = threadIdx.x;
    const int e0 = blockIdx.x * CHUNK;
    const int cnt = min(CHUNK, E - e0);

    h[t] = 0;
    __syncthreads();
    for (int i = t; i < cnt; i += 256) atomicAdd(&h[ec[e0 + i] >> BSH], 1);
    __syncthreads();
    int v = h[t];
    s[t] = v; __syncthreads();
    for (int off = 1; off < 256; off <<= 1) {
        int x = (t >= off) ? s[t - off] : 0;
        __syncthreads();
        s[t] += x;
        __syncthreads();
    }
    lbase[t] = s[t] - v;
    cur[t] = s[t] - v;
    segd[t] = atomicAdd(&globCursor[t], v) - lbase[t];
    __syncthreads();
    for (int i = t; i < cnt; i += 256) {
        int c = ec[e0 + i];
        int b = c >> BSH;
        int p = atomicAdd(&cur[b], 1);
        stage[p] = make_int2(er[e0 + i], c);
    }
    __syncthreads();
    for (int i = t; i < cnt; i += 256) {
        int2 pr = stage[i];
        int b = pr.y >> BSH;
        pairs[segd[b] + i] = pr;
    }
}

// one block per bucket. LDS hist+scan -> rowptr, dinv, slot fill.
// R15: also scales the bf16 x-cast (Hb0) rows of this bucket by dinv in
// place (S = dinv * x), so every layer uses the pre-scaled gather path.
__global__ __launch_bounds__(256) void fill_csr(const int2* __restrict__ pairs,
                                                const int* __restrict__ bucketBase,
                                                const int* __restrict__ bucketCnt,
                                                int N, int E, int NBUCK,
                                                int* __restrict__ rowptr,
                                                float* __restrict__ dinv,
                                                int* __restrict__ srcs,
                                                unsigned short* __restrict__ Hb0) {
    __shared__ int hist[512], lofs[512], s[256];
    const int t = threadIdx.x;
    const int b = blockIdx.x;
    const int c0 = b << BSH;
    const int base = bucketBase[b];
    const int cnt = bucketCnt[b];
    const int2* pp = pairs + base;

    hist[t] = 0; hist[t + 256] = 0;
    __syncthreads();
    for (int i = t; i < cnt; i += 256) atomicAdd(&hist[pp[i].y - c0], 1);
    __syncthreads();
    int a0 = hist[2 * t], a1 = hist[2 * t + 1];
    s[t] = a0 + a1; __syncthreads();
    for (int off = 1; off < 256; off <<= 1) {
        int x = (t >= off) ? s[t - off] : 0;
        __syncthreads();
        s[t] += x;
        __syncthreads();
    }
    int excl = s[t] - (a0 + a1);
    lofs[2 * t] = excl;
    lofs[2 * t + 1] = excl + a0;
    __syncthreads();
    const int nn = min(512, N - c0);
    for (int i = t; i < nn; i += 256) {
        rowptr[c0 + i] = base + lofs[i];
        dinv[c0 + i] = rsqrtf((float)hist[i] + 1.0f);
    }
    if (b == NBUCK - 1 && t == 0) rowptr[N] = E;
    __syncthreads();
    for (int i = t; i < cnt; i += 256) {
        int2 pr = pp[i];
        int p = atomicAdd(&lofs[pr.y - c0], 1);
        srcs[base + p] = pr.x;
    }
    // ---- scale Hb0 rows of this bucket by dinv (S = dinv * x) ----
    unsigned int* Hrow = (unsigned int*)Hb0 + (size_t)c0 * 64;   // 64 dwords/row
    for (int i = t; i < nn * 64; i += 256) {
        int r = i >> 6;
        float dv = rsqrtf((float)hist[r] + 1.0f);
        unsigned int v = Hrow[i];
        unsigned short lo = f2bf(bf2f((unsigned short)(v & 0xFFFFu)) * dv);
        unsigned short hi = f2bf(bf2f((unsigned short)(v >> 16)) * dv);
        Hrow[i] = ((unsigned int)hi << 16) | lo;
    }
}

// ---------------------------------------------------------------------------
// Fused layer: ONE WAVE per block, 16 target rows.
// Phase A: 4 sixteen-lane groups; group `quad` aggregates rows quad*4..+3,
//   one at a time; lane owns one 16B chunk of the 256B source row.
//   8-edge batches: indices via two dwordx4 loads (prefetched 1 batch
//   ahead), invalid slots clamped to self with weight 0 (uniform masked
//   tail, no serial remainder). Inputs are pre-scaled S = dinv*h, so
//   P = dinv[row]*(sum S[src] + S[row]) needs no per-edge dinv.
//   Result row written bf16 into the xor-swizzled LDS A-tile.
// Phase B: 16x16 MFMA gemm; A-frags from LDS (conflict-free ds_read_b128),
//   W-frags from global (L2-hot). Epilogue folds bias+relu+output-dinv
//   pre-scale; LDS reused as out tile (pitch OP) -> coalesced 16B stores.
//   Layer 4 (writeDots): head dot fused, no Hn write.
// C/D: col=lane&15, row=(lane>>4)*4+reg (verified mapping).
// ---------------------------------------------------------------------------
__global__ __launch_bounds__(64, 8) void layer_fused(
        const int* __restrict__ rowptr, const int* __restrict__ srcs,
        const float* __restrict__ dinv, const unsigned short* __restrict__ H,
        const unsigned short* __restrict__ Wt, const float* __restrict__ bias,
        unsigned short* __restrict__ Hn, float* __restrict__ dots,
        const float* __restrict__ Wl, int N, int writeDots) {
    __shared__ __align__(16) unsigned short U[16 * OP];   // 4.25 KB
    const int lane = threadIdx.x;        // 0..63
    const int row16 = lane & 15;
    const int quad = lane >> 4;
    const int r0 = blockIdx.x * 16;
    const bf16x8* H8 = (const bf16x8*)H;     // 16 chunks (16B) per row
    const int gl = row16;                    // chunk index this lane owns

    // ---- phase A: aggregate 16 rows into swizzled LDS A-tile ----
    for (int sstep = 0; sstep < 4; ++sstep) {
        const int rt = quad * 4 + sstep;     // local row 0..15
        const int row = r0 + rt;
        f32x2 acc[4] = {{0.f, 0.f}, {0.f, 0.f}, {0.f, 0.f}, {0.f, 0.f}};
        float sn = 0.f;
        if (row < N) {
            sn = dinv[row];
            int j = rowptr[row];
            const int end = rowptr[row + 1];
            {   // self term (pre-scaled)
                union { bf16x8 v; unsigned int d[4]; } sv;
                sv.v = H8[(size_t)row * 16 + gl];
#pragma unroll
                for (int i = 0; i < 4; ++i) acc[i] = unpk(sv.d[i]);
            }
            const int nb = (end - j + 7) >> 3;     // masked 8-edge batches
            i32x4u ia, ib;
            if (nb > 0) {
                const i32x4u* sp = (const i32x4u*)(srcs + j);
                ia = sp[0]; ib = sp[1];
            }
            for (int b = 0; b < nb; ++b) {
                const int jb = j + b * 8;
                int r[8]; float w[8];
#pragma unroll
                for (int t = 0; t < 8; ++t) {
                    int idx = (t < 4) ? ia[t] : ib[t - 4];
                    bool val = (jb + t) < end;
                    r[t] = val ? idx : row;        // clamp to a valid row
                    w[t] = val ? 1.f : 0.f;
                }
                bf16x8 h[8];
#pragma unroll
                for (int t = 0; t < 8; ++t) h[t] = H8[(size_t)r[t] * 16 + gl];
                if (b + 1 < nb) {                  // prefetch next indices
                    const i32x4u* sp = (const i32x4u*)(srcs + jb + 8);
                    ia = sp[0]; ib = sp[1];
                }
#pragma unroll
                for (int t = 0; t < 8; ++t) {
                    union { bf16x8 v; unsigned int d[4]; } cv;
                    cv.v = h[t];
                    f32x2 w2 = {w[t], w[t]};
#pragma unroll
                    for (int i = 0; i < 4; ++i) acc[i] += unpk(cv.d[i]) * w2;
                }
            }
        }
        // P row (bf16) -> swizzled A-tile; rows >= N become zeros (sn=0)
        bf16x8 o;
#pragma unroll
        for (int i = 0; i < 4; ++i) {
            o[2 * i]     = (short)f2bf(sn * acc[i].x);
            o[2 * i + 1] = (short)f2bf(sn * acc[i].y);
        }
        *(bf16x8*)(U + rt * 128 + ((gl ^ rt) << 3)) = o;
    }
    __syncthreads();   // 1-wave block: compiles to cnt drain, no stall

    // ---- phase B: A fragments, all 4 K-chunks ----
    bf16x8 a0[4];
#pragma unroll
    for (int kc = 0; kc < 4; ++kc) {
        const int ph = (kc * 4 + quad) ^ row16;
        a0[kc] = *(const bf16x8*)(U + row16 * 128 + ph * 8);
    }
    __syncthreads();   // U is now reused as the out tile (pitch OP)

    // dinv of output rows (pre-scale stored features); not needed for dots
    float dv[4];
    if (!writeDots) {
#pragma unroll
        for (int i = 0; i < 4; ++i) {
            int ra = r0 + quad * 4 + i;
            dv[i] = (ra < N) ? dinv[ra] : 0.f;
        }
    }

    float rd[4] = {0.f, 0.f, 0.f, 0.f};
#pragma unroll
    for (int ct = 0; ct < 8; ++ct) {
        const int col = ct * 16 + row16;
        const bf16x8* wc = (const bf16x8*)(Wt + (size_t)col * 128);
        f32x4 acc0 = {0.f, 0.f, 0.f, 0.f};
#pragma unroll
        for (int kc = 0; kc < 4; ++kc) {
            const bf16x8 wf = wc[kc * 4 + quad];
            acc0 = __builtin_amdgcn_mfma_f32_16x16x32_bf16(a0[kc], wf, acc0, 0, 0, 0);
        }
        const float bv = bias[col];
        if (writeDots) {
            const float wl = Wl[col];
#pragma unroll
            for (int i = 0; i < 4; ++i) rd[i] += fmaxf(acc0[i] + bv, 0.f) * wl;
        } else {
#pragma unroll
            for (int i = 0; i < 4; ++i)
                U[(quad * 4 + i) * OP + col] = f2bf(dv[i] * fmaxf(acc0[i] + bv, 0.f));
        }
    }

    if (writeDots) {
#pragma unroll
        for (int m = 1; m < 16; m <<= 1)
#pragma unroll
            for (int i = 0; i < 4; ++i) rd[i] += __shfl_xor(rd[i], m, 64);
        if (row16 == 0) {
#pragma unroll
            for (int i = 0; i < 4; ++i) dots[r0 + quad * 4 + i] = rd[i];
        }
    } else {
        __syncthreads();
        // coalesced readback + store: 256 16B chunks per tile, 4/lane
#pragma unroll
        for (int i = 0; i < 4; ++i) {
            int idx = i * 64 + lane;
            int row = idx >> 4, c8 = idx & 15;
            bf16x8 v = *(const bf16x8*)(U + row * OP + c8 * 8);
            *(bf16x8*)(Hn + (size_t)(r0 + row) * 128 + c8 * 8) = v;
        }
    }
}

// one block per graph: binary-search node range in sorted batch, mean, +bl
__global__ __launch_bounds__(256) void pool_graphs(const float* __restrict__ dots,
                                                   const int* __restrict__ batch, int N,
                                                   const float* __restrict__ bl,
                                                   float* __restrict__ out) {
    __shared__ int bounds[2];
    __shared__ float red[4];
    const int g = blockIdx.x;
    const int t = threadIdx.x;
    if (t < 2) {
        int key = g + t;             // lower_bound(batch, key)
        int lo = 0, hi = N;
        while (lo < hi) {
            int mid = (lo + hi) >> 1;
            if (batch[mid] < key) lo = mid + 1; else hi = mid;
        }
        bounds[t] = lo;
    }
    __syncthreads();
    const int lo = bounds[0], hi = bounds[1];
    float s = 0.f;
    for (int i = lo + t; i < hi; i += 256) s += dots[i];
#pragma unroll
    for (int off = 32; off > 0; off >>= 1) s += __shfl_down(s, off, 64);
    if ((t & 63) == 0) red[t >> 6] = s;
    __syncthreads();
    if (t == 0) {
        float tot = red[0] + red[1] + red[2] + red[3];
        int cnt = hi - lo;
        out[g] = tot / (float)(cnt > 0 ? cnt : 1) + bl[0];
    }
}

extern "C" void kernel_launch(void* const* d_in, const int* in_sizes, int n_in,
                              void* d_out, int out_size, void* d_ws, size_t ws_size,
                              hipStream_t stream) {
    const float* x     = (const float*)d_in[0];
    const int*   eidx  = (const int*)d_in[1];    // int32 (harness converts int64)
    const int*   batch = (const int*)d_in[2];
    const float* Ws    = (const float*)d_in[3];
    const float* bs    = (const float*)d_in[4];
    const float* Wl    = (const float*)d_in[5];
    const float* bl    = (const float*)d_in[6];
    (void)n_in; (void)out_size;

    const int N = in_sizes[0] / D;
    const int E = in_sizes[1] / 2;
    const int* er = eidx;       // sources
    const int* ec = eidx + E;   // targets
    const int NBUCK = (N + 511) >> BSH;          // 512-node buckets (<= 256)
    const int NCHUNK = (E + CHUNK - 1) / CHUNK;

    // ---- workspace carve ----
    const int Npad = (N + 127) & ~127;
    const size_t hBytes = (size_t)Npad * D * sizeof(unsigned short); // 25.6 MB bf16
    auto al = [](size_t v) { return (v + 255) & ~(size_t)255; };
    char* base = (char*)d_ws;
    size_t off = 0;

    unsigned short* Hb0 = (unsigned short*)base; off = al(hBytes);
    int* bucketCnt  = (int*)(base + off);
    int* globCursor = bucketCnt + 256;
    off = al(off + 512 * sizeof(int));
    int*   bucketBase = (int*)(base + off);  off = al(off + 256 * sizeof(int));
    float* dinv   = (float*)(base + off);    off = al(off + (size_t)Npad * sizeof(float));
    float* dots   = (float*)(base + off);    off = al(off + (size_t)Npad * sizeof(float));
    int*   rowptr = (int*)(base + off);      off = al(off + (size_t)(Npad + 64) * sizeof(int));
    int*   srcs   = (int*)(base + off);      off = al(off + (size_t)E * sizeof(int) + 64);
    unsigned short* Wt = (unsigned short*)(base + off);   off = al(off + 4 * 128 * 128 * sizeof(unsigned short));

    // second bf16 buffer: in ws if it fits, else reuse x's 51.2 MB input buffer
    // (Npad*256B <= N*512B, so the alias stays in-bounds). pairs aliases Hb1:
    // CSR build completes before layer-1 gemm writes Hb1 (same stream).
    const bool twoBuf = ws_size >= off + hBytes;
    unsigned short* Hb1 = twoBuf ? (unsigned short*)(base + off)
                                 : (unsigned short*)d_in[0];
    int2* pairs = (int2*)Hb1;
    unsigned short* hb[2] = { Hb0, Hb1 };

    // ---- setup: memset bucketCnt; merged cast_x | cast_W | histogram ----
    hipMemsetAsync(bucketCnt, 0, 256 * sizeof(int), stream);
    const int n4 = N * D / 4;
    const int CB = (n4 + 255) / 256;
    setup_all<<<CB + 256 + NCHUNK, 256, 0, stream>>>((const float4*)x, (ushort4*)Hb0,
                                                     n4, CB, Ws, Wt, ec, E, bucketCnt);

    // ---- binned CSR build (once; reused by all 4 layers) ----
    bucket_scan<<<1, 256, 0, stream>>>(bucketCnt, bucketBase, globCursor);
    scatter_pairs<<<NCHUNK, 256, 0, stream>>>(er, ec, E, globCursor, pairs);
    fill_csr<<<NBUCK, 256, 0, stream>>>(pairs, bucketBase, bucketCnt, N, E, NBUCK,
                                        rowptr, dinv, srcs, Hb0);

    // ---- 4 fused layers: aggregate -> LDS A-tile -> MFMA (-> head dot) ----
    for (int i = 0; i < 4; ++i) {
        const unsigned short* Hc = hb[i & 1];
        unsigned short* Hn = hb[(i + 1) & 1];
        layer_fused<<<Npad / 16, 64, 0, stream>>>(rowptr, srcs, dinv, Hc,
                                                  Wt + (size_t)i * D * D,
                                                  bs + (size_t)i * D, Hn, dots, Wl,
                                                  N, (i == 3) ? 1 : 0);
    }

    // ---- mean pool (+bl) over fused per-node dots ----
    pool_graphs<<<NGRAPH, 256, 0, stream>>>(dots, batch, N, bl, (float*)d_out);
}

// Round 4
// 578.061 us; speedup vs baseline: 1.0664x; 1.0664x over previous
//
#include <hip/hip_runtime.h>

// ---------------------------------------------------------------------------
// GCN forward, reassociated: per layer h = relu( (A_hat h) W + b ).
// R16 = R14's proven gather loop + R15's good geometry, minus R15's bug.
// R15 post-mortem: __launch_bounds__(64,8) clamped VGPR to 64 -> compiler
// spilled the gather batches to scratch (WRITE_SIZE 25->111 MB, FETCH
// +52 MB = spill traffic). Fix: __launch_bounds__(64,4) (128-VGPR budget,
// no spills; R14's loop measured 52 VGPR) while keeping:
//  - 16 rows per 1-wave block (grid 6256 = 24 blocks/CU avg; R14's 3128
//    blocks were the occupancy cap at 29%).
//  - ALL layers pre-scaled (fill_csr scales bf16 x-cast by dinv in place),
//    so the per-edge gather has no dinv load anywhere; one code path.
// Epilogue folds bias+relu+output-dinv; layer 4 fuses the head dot.
// CSR build (binned, atomic-free hot path) unchanged. pairs aliases Hb1.
// NOTE: harness delivers integer inputs as int32 (edge_index/batch: int*).
// ---------------------------------------------------------------------------

constexpr int D = 128;
constexpr int NGRAPH = 512;
constexpr int CHUNK = 4096;       // edges per scatter block
constexpr int BSH = 9;            // 512 nodes per bucket
constexpr int OP = 136;           // out-tile pitch (ushorts): 272B, 16B-aligned rows

typedef __attribute__((ext_vector_type(8))) short bf16x8;
typedef __attribute__((ext_vector_type(4))) float f32x4;

__device__ __forceinline__ float bf2f(unsigned short b) {
    return __uint_as_float(((unsigned int)b) << 16);
}
__device__ __forceinline__ unsigned short f2bf(float f) {   // round-to-nearest-even
    unsigned int u = __float_as_uint(f);
    u += 0x7FFFu + ((u >> 16) & 1u);
    return (unsigned short)(u >> 16);
}

// merged independent setup: [0,CB) cast x->bf16 | [CB,CB+256) cast W ->
// transposed bf16 Wt | [CB+256, ...) per-chunk bucket histogram.
__global__ __launch_bounds__(256) void setup_all(
        const float4* __restrict__ x4, ushort4* __restrict__ hb, int n4, int CB,
        const float* __restrict__ W, unsigned short* __restrict__ Wt,
        const int* __restrict__ ec, int E, int* __restrict__ bucketCnt) {
    __shared__ int h[256];
    const int t = threadIdx.x;
    const int b = blockIdx.x;
    if (b < CB) {
        int i = b * 256 + t;
        if (i < n4) {
            float4 v = x4[i];
            ushort4 o;
            o.x = f2bf(v.x); o.y = f2bf(v.y); o.z = f2bf(v.z); o.w = f2bf(v.w);
            hb[i] = o;
        }
    } else if (b < CB + 256) {
        int idx = (b - CB) * 256 + t;      // 4*128*128 = 65536 elems
        int i = idx >> 14;
        int rem = idx & 16383;
        int k = rem >> 7, c = rem & 127;
        Wt[(i << 14) + c * 128 + k] = f2bf(W[idx]);
    } else {
        h[t] = 0;
        __syncthreads();
        const int e0 = (b - CB - 256) * CHUNK;
        const int cnt = min(CHUNK, E - e0);
        for (int i = t; i < cnt; i += 256) atomicAdd(&h[ec[e0 + i] >> BSH], 1);
        __syncthreads();
        if (h[t]) atomicAdd(&bucketCnt[t], h[t]);
    }
}

// exclusive scan over 256 bucket counts -> bucketBase, globCursor
__global__ __launch_bounds__(256) void bucket_scan(const int* __restrict__ bucketCnt,
                                                   int* __restrict__ bucketBase,
                                                   int* __restrict__ globCursor) {
    __shared__ int s[256];
    const int t = threadIdx.x;
    int v = bucketCnt[t];
    s[t] = v; __syncthreads();
    for (int off = 1; off < 256; off <<= 1) {
        int x = (t >= off) ? s[t - off] : 0;
        __syncthreads();
        s[t] += x;
        __syncthreads();
    }
    int excl = s[t] - v;
    bucketBase[t] = excl;
    globCursor[t] = excl;
}

// scatter (r,c) pairs into bucket-grouped array, LDS-staged & coalesced
__global__ __launch_bounds__(256) void scatter_pairs(const int* __restrict__ er,
                                                     const int* __restrict__ ec, int E,
                                                     int* __restrict__ globCursor,
                                                     int2* __restrict__ pairs) {
    __shared__ int h[256], lbase[256], cur[256], segd[256], s[256];
    __shared__ int2 stage[CHUNK];
    const int t = threadIdx.x;
    const int e0 = blockIdx.x * CHUNK;
    const int cnt = min(CHUNK, E - e0);

    h[t] = 0;
    __syncthreads();
    for (int i = t; i < cnt; i += 256) atomicAdd(&h[ec[e0 + i] >> BSH], 1);
    __syncthreads();
    int v = h[t];
    s[t] = v; __syncthreads();
    for (int off = 1; off < 256; off <<= 1) {
        int x = (t >= off) ? s[t - off] : 0;
        __syncthreads();
        s[t] += x;
        __syncthreads();
    }
    lbase[t] = s[t] - v;
    cur[t] = s[t] - v;
    segd[t] = atomicAdd(&globCursor[t], v) - lbase[t];
    __syncthreads();
    for (int i = t; i < cnt; i += 256) {
        int c = ec[e0 + i];
        int b = c >> BSH;
        int p = atomicAdd(&cur[b], 1);
        stage[p] = make_int2(er[e0 + i], c);
    }
    __syncthreads();
    for (int i = t; i < cnt; i += 256) {
        int2 pr = stage[i];
        int b = pr.y >> BSH;
        pairs[segd[b] + i] = pr;
    }
}

// one block per bucket. LDS hist+scan -> rowptr, dinv, slot fill.
// Also scales the bf16 x-cast (Hb0) rows of this bucket by dinv in place
// (S = dinv * x), so every layer uses the pre-scaled gather path.
__global__ __launch_bounds__(256) void fill_csr(const int2* __restrict__ pairs,
                                                const int* __restrict__ bucketBase,
                                                const int* __restrict__ bucketCnt,
                                                int N, int E, int NBUCK,
                                                int* __restrict__ rowptr,
                                                float* __restrict__ dinv,
                                                int* __restrict__ srcs,
                                                unsigned short* __restrict__ Hb0) {
    __shared__ int hist[512], lofs[512], s[256];
    const int t = threadIdx.x;
    const int b = blockIdx.x;
    const int c0 = b << BSH;
    const int base = bucketBase[b];
    const int cnt = bucketCnt[b];
    const int2* pp = pairs + base;

    hist[t] = 0; hist[t + 256] = 0;
    __syncthreads();
    for (int i = t; i < cnt; i += 256) atomicAdd(&hist[pp[i].y - c0], 1);
    __syncthreads();
    int a0 = hist[2 * t], a1 = hist[2 * t + 1];
    s[t] = a0 + a1; __syncthreads();
    for (int off = 1; off < 256; off <<= 1) {
        int x = (t >= off) ? s[t - off] : 0;
        __syncthreads();
        s[t] += x;
        __syncthreads();
    }
    int excl = s[t] - (a0 + a1);
    lofs[2 * t] = excl;
    lofs[2 * t + 1] = excl + a0;
    __syncthreads();
    const int nn = min(512, N - c0);
    for (int i = t; i < nn; i += 256) {
        rowptr[c0 + i] = base + lofs[i];
        dinv[c0 + i] = rsqrtf((float)hist[i] + 1.0f);
    }
    if (b == NBUCK - 1 && t == 0) rowptr[N] = E;
    __syncthreads();
    for (int i = t; i < cnt; i += 256) {
        int2 pr = pp[i];
        int p = atomicAdd(&lofs[pr.y - c0], 1);
        srcs[base + p] = pr.x;
    }
    // ---- scale Hb0 rows of this bucket by dinv (S = dinv * x) ----
    unsigned int* Hrow = (unsigned int*)Hb0 + (size_t)c0 * 64;   // 64 dwords/row
    for (int i = t; i < nn * 64; i += 256) {
        int r = i >> 6;
        float dv = rsqrtf((float)hist[r] + 1.0f);
        unsigned int v = Hrow[i];
        unsigned short lo = f2bf(bf2f((unsigned short)(v & 0xFFFFu)) * dv);
        unsigned short hi = f2bf(bf2f((unsigned short)(v >> 16)) * dv);
        Hrow[i] = ((unsigned int)hi << 16) | lo;
    }
}

// ---------------------------------------------------------------------------
// Fused layer: ONE WAVE per block, 16 target rows.
// Phase A: 4 sixteen-lane groups; group `quad` aggregates rows quad*4..+3,
//   one at a time; lane owns one 16B chunk of the 256B source row (8-edge
//   unrolled gather batches + short serial tail — R14's proven loop, 52
//   VGPR, no spills). Inputs pre-scaled S = dinv*h, so no per-edge dinv.
//   Result P = dinv[row]*(sum S[src] + S[row]) written bf16 into the
//   xor-swizzled LDS A-tile (pitch 128, chunk pos = gl ^ row).
// Phase B: 16x16 MFMA gemm; A-frags from LDS (conflict-free ds_read_b128),
//   W-frags from global (L2-hot). Epilogue folds bias+relu+output-dinv;
//   LDS reused as out tile (pitch OP) -> coalesced 16B stores.
//   Layer 4 (writeDots): head dot fused, no Hn write.
// __launch_bounds__(64,4): 128-VGPR budget — concurrency comes from the
// grid (6256 blocks = 24/CU), NOT from a register clamp (R15's mistake).
// C/D: col=lane&15, row=(lane>>4)*4+reg (verified mapping).
// ---------------------------------------------------------------------------
__global__ __launch_bounds__(64, 4) void layer_fused(
        const int* __restrict__ rowptr, const int* __restrict__ srcs,
        const float* __restrict__ dinv, const unsigned short* __restrict__ H,
        const unsigned short* __restrict__ Wt, const float* __restrict__ bias,
        unsigned short* __restrict__ Hn, float* __restrict__ dots,
        const float* __restrict__ Wl, int N, int writeDots) {
    __shared__ __align__(16) unsigned short U[16 * OP];   // 4.25 KB
    const int lane = threadIdx.x;        // 0..63
    const int row16 = lane & 15;
    const int quad = lane >> 4;
    const int r0 = blockIdx.x * 16;
    const bf16x8* H8 = (const bf16x8*)H;     // 16 chunks (16B) per row
    const int gl = row16;                    // chunk index this lane owns

    // ---- phase A: aggregate 16 rows into swizzled LDS A-tile ----
    for (int sstep = 0; sstep < 4; ++sstep) {
        const int rt = quad * 4 + sstep;     // local row 0..15
        const int row = r0 + rt;
        float acc[8] = {0.f, 0.f, 0.f, 0.f, 0.f, 0.f, 0.f, 0.f};
        float sn = 0.f;
        if (row < N) {
            sn = dinv[row];
            int j = rowptr[row];
            const int end = rowptr[row + 1];
            // self-loop term (pre-scaled)
            bf16x8 hv = H8[(size_t)row * 16 + gl];
#pragma unroll
            for (int k = 0; k < 8; ++k) acc[k] = bf2f((unsigned short)hv[k]);
            for (; j + 8 <= end; j += 8) {
                int r[8]; bf16x8 h[8];
#pragma unroll
                for (int t = 0; t < 8; ++t) r[t] = srcs[j + t];
#pragma unroll
                for (int t = 0; t < 8; ++t) h[t] = H8[(size_t)r[t] * 16 + gl];
#pragma unroll
                for (int t = 0; t < 8; ++t)
#pragma unroll
                    for (int k = 0; k < 8; ++k)
                        acc[k] += bf2f((unsigned short)h[t][k]);
            }
            for (; j < end; ++j) {
                bf16x8 h0 = H8[(size_t)srcs[j] * 16 + gl];
#pragma unroll
                for (int k = 0; k < 8; ++k)
                    acc[k] += bf2f((unsigned short)h0[k]);
            }
        }
        // P row (bf16) -> swizzled A-tile; rows >= N become zeros (sn=0)
        bf16x8 o;
#pragma unroll
        for (int k = 0; k < 8; ++k) o[k] = (short)f2bf(sn * acc[k]);
        *(bf16x8*)(U + rt * 128 + ((gl ^ rt) << 3)) = o;
    }
    __syncthreads();   // 1-wave block: compiles to cnt drain, no stall

    // ---- phase B: A fragments, all 4 K-chunks ----
    bf16x8 a0[4];
#pragma unroll
    for (int kc = 0; kc < 4; ++kc) {
        const int ph = (kc * 4 + quad) ^ row16;
        a0[kc] = *(const bf16x8*)(U + row16 * 128 + ph * 8);
    }
    __syncthreads();   // U is now reused as the out tile (pitch OP)

    // dinv of output rows (pre-scale stored features); not needed for dots
    float dv[4];
    if (!writeDots) {
#pragma unroll
        for (int i = 0; i < 4; ++i) {
            int ra = r0 + quad * 4 + i;
            dv[i] = (ra < N) ? dinv[ra] : 0.f;
        }
    }

    float rd[4] = {0.f, 0.f, 0.f, 0.f};
#pragma unroll
    for (int ct = 0; ct < 8; ++ct) {
        const int col = ct * 16 + row16;
        const bf16x8* wc = (const bf16x8*)(Wt + (size_t)col * 128);
        f32x4 acc0 = {0.f, 0.f, 0.f, 0.f};
#pragma unroll
        for (int kc = 0; kc < 4; ++kc) {
            const bf16x8 wf = wc[kc * 4 + quad];
            acc0 = __builtin_amdgcn_mfma_f32_16x16x32_bf16(a0[kc], wf, acc0, 0, 0, 0);
        }
        const float bv = bias[col];
        if (writeDots) {
            const float wl = Wl[col];
#pragma unroll
            for (int i = 0; i < 4; ++i) rd[i] += fmaxf(acc0[i] + bv, 0.f) * wl;
        } else {
#pragma unroll
            for (int i = 0; i < 4; ++i)
                U[(quad * 4 + i) * OP + col] = f2bf(dv[i] * fmaxf(acc0[i] + bv, 0.f));
        }
    }

    if (writeDots) {
#pragma unroll
        for (int m = 1; m < 16; m <<= 1)
#pragma unroll
            for (int i = 0; i < 4; ++i) rd[i] += __shfl_xor(rd[i], m, 64);
        if (row16 == 0) {
#pragma unroll
            for (int i = 0; i < 4; ++i) dots[r0 + quad * 4 + i] = rd[i];
        }
    } else {
        __syncthreads();
        // coalesced readback + store: 256 16B chunks per tile, 4/lane
#pragma unroll
        for (int i = 0; i < 4; ++i) {
            int idx = i * 64 + lane;
            int row = idx >> 4, c8 = idx & 15;
            bf16x8 v = *(const bf16x8*)(U + row * OP + c8 * 8);
            *(bf16x8*)(Hn + (size_t)(r0 + row) * 128 + c8 * 8) = v;
        }
    }
}

// one block per graph: binary-search node range in sorted batch, mean, +bl
__global__ __launch_bounds__(256) void pool_graphs(const float* __restrict__ dots,
                                                   const int* __restrict__ batch, int N,
                                                   const float* __restrict__ bl,
                                                   float* __restrict__ out) {
    __shared__ int bounds[2];
    __shared__ float red[4];
    const int g = blockIdx.x;
    const int t = threadIdx.x;
    if (t < 2) {
        int key = g + t;             // lower_bound(batch, key)
        int lo = 0, hi = N;
        while (lo < hi) {
            int mid = (lo + hi) >> 1;
            if (batch[mid] < key) lo = mid + 1; else hi = mid;
        }
        bounds[t] = lo;
    }
    __syncthreads();
    const int lo = bounds[0], hi = bounds[1];
    float s = 0.f;
    for (int i = lo + t; i < hi; i += 256) s += dots[i];
#pragma unroll
    for (int off = 32; off > 0; off >>= 1) s += __shfl_down(s, off, 64);
    if ((t & 63) == 0) red[t >> 6] = s;
    __syncthreads();
    if (t == 0) {
        float tot = red[0] + red[1] + red[2] + red[3];
        int cnt = hi - lo;
        out[g] = tot / (float)(cnt > 0 ? cnt : 1) + bl[0];
    }
}

extern "C" void kernel_launch(void* const* d_in, const int* in_sizes, int n_in,
                              void* d_out, int out_size, void* d_ws, size_t ws_size,
                              hipStream_t stream) {
    const float* x     = (const float*)d_in[0];
    const int*   eidx  = (const int*)d_in[1];    // int32 (harness converts int64)
    const int*   batch = (const int*)d_in[2];
    const float* Ws    = (const float*)d_in[3];
    const float* bs    = (const float*)d_in[4];
    const float* Wl    = (const float*)d_in[5];
    const float* bl    = (const float*)d_in[6];
    (void)n_in; (void)out_size;

    const int N = in_sizes[0] / D;
    const int E = in_sizes[1] / 2;
    const int* er = eidx;       // sources
    const int* ec = eidx + E;   // targets
    const int NBUCK = (N + 511) >> BSH;          // 512-node buckets (<= 256)
    const int NCHUNK = (E + CHUNK - 1) / CHUNK;

    // ---- workspace carve ----
    const int Npad = (N + 127) & ~127;
    const size_t hBytes = (size_t)Npad * D * sizeof(unsigned short); // 25.6 MB bf16
    auto al = [](size_t v) { return (v + 255) & ~(size_t)255; };
    char* base = (char*)d_ws;
    size_t off = 0;

    unsigned short* Hb0 = (unsigned short*)base; off = al(hBytes);
    int* bucketCnt  = (int*)(base + off);
    int* globCursor = bucketCnt + 256;
    off = al(off + 512 * sizeof(int));
    int*   bucketBase = (int*)(base + off);  off = al(off + 256 * sizeof(int));
    float* dinv   = (float*)(base + off);    off = al(off + (size_t)Npad * sizeof(float));
    float* dots   = (float*)(base + off);    off = al(off + (size_t)Npad * sizeof(float));
    int*   rowptr = (int*)(base + off);      off = al(off + (size_t)(Npad + 64) * sizeof(int));
    int*   srcs   = (int*)(base + off);      off = al(off + (size_t)E * sizeof(int) + 64);
    unsigned short* Wt = (unsigned short*)(base + off);   off = al(off + 4 * 128 * 128 * sizeof(unsigned short));

    // second bf16 buffer: in ws if it fits, else reuse x's 51.2 MB input buffer
    // (Npad*256B <= N*512B, so the alias stays in-bounds). pairs aliases Hb1:
    // CSR build completes before layer-1 gemm writes Hb1 (same stream).
    const bool twoBuf = ws_size >= off + hBytes;
    unsigned short* Hb1 = twoBuf ? (unsigned short*)(base + off)
                                 : (unsigned short*)d_in[0];
    int2* pairs = (int2*)Hb1;
    unsigned short* hb[2] = { Hb0, Hb1 };

    // ---- setup: memset bucketCnt; merged cast_x | cast_W | histogram ----
    hipMemsetAsync(bucketCnt, 0, 256 * sizeof(int), stream);
    const int n4 = N * D / 4;
    const int CB = (n4 + 255) / 256;
    setup_all<<<CB + 256 + NCHUNK, 256, 0, stream>>>((const float4*)x, (ushort4*)Hb0,
                                                     n4, CB, Ws, Wt, ec, E, bucketCnt);

    // ---- binned CSR build (once; reused by all 4 layers) ----
    bucket_scan<<<1, 256, 0, stream>>>(bucketCnt, bucketBase, globCursor);
    scatter_pairs<<<NCHUNK, 256, 0, stream>>>(er, ec, E, globCursor, pairs);
    fill_csr<<<NBUCK, 256, 0, stream>>>(pairs, bucketBase, bucketCnt, N, E, NBUCK,
                                        rowptr, dinv, srcs, Hb0);

    // ---- 4 fused layers: aggregate -> LDS A-tile -> MFMA (-> head dot) ----
    for (int i = 0; i < 4; ++i) {
        const unsigned short* Hc = hb[i & 1];
        unsigned short* Hn = hb[(i + 1) & 1];
        layer_fused<<<Npad / 16, 64, 0, stream>>>(rowptr, srcs, dinv, Hc,
                                                  Wt + (size_t)i * D * D,
                                                  bs + (size_t)i * D, Hn, dots, Wl,
                                                  N, (i == 3) ? 1 : 0);
    }

    // ---- mean pool (+bl) over fused per-node dots ----
    pool_graphs<<<NGRAPH, 256, 0, stream>>>(dots, batch, N, bl, (float*)d_out);
}

// Round 5
// 512.914 us; speedup vs baseline: 1.2019x; 1.1270x over previous
//
#include <hip/hip_runtime.h>

// ---------------------------------------------------------------------------
// GCN forward, reassociated: per layer h = relu( (A_hat h) W + b ).
// R17: depth-2 software pipeline in the gather (phase A).
// R16 post-mortem: 437 cyc/edge — the batch loop was a serial chain
// srcs->wait->h->wait->consume (~1500 cyc / 8 edges). Now per iteration:
//   (1) compute next-batch indices (waits srcs(b+1), issued LAST iter,
//       BEFORE h(b) so the wait doesn't drain the h queue),
//   (2) issue srcs(b+2), (3) issue h(b+1), (4) consume h(b) while h(b+1)
//   flies. Steady state ~900 cyc / 32 edge-gathers per wave.
// Tail: masked final batch (index clamped to self row, weight recomputed
// from remaining-count at consume; no stored weight arrays) — kills the
// serial <8-edge tail that dominated row time.
// #pragma unroll 1 on batch+row loops: keep live set ~105 VGPR under the
// (64,4) 128 cap — R15's spill was clamp(64,8) + implicit unroll.
// Geometry from R16: 16 rows per 1-wave block, grid 6256. All layers
// pre-scaled (fill_csr scales bf16 x-cast by dinv in place).
// Epilogue folds bias+relu+output-dinv; layer 4 fuses the head dot.
// NOTE: harness delivers integer inputs as int32 (edge_index/batch: int*).
// ---------------------------------------------------------------------------

constexpr int D = 128;
constexpr int NGRAPH = 512;
constexpr int CHUNK = 4096;       // edges per scatter block
constexpr int BSH = 9;            // 512 nodes per bucket
constexpr int OP = 136;           // out-tile pitch (ushorts): 272B, 16B-aligned rows

typedef __attribute__((ext_vector_type(8))) short bf16x8;
typedef __attribute__((ext_vector_type(4))) float f32x4;
typedef int i32x4u __attribute__((ext_vector_type(4), aligned(4)));

__device__ __forceinline__ float bf2f(unsigned short b) {
    return __uint_as_float(((unsigned int)b) << 16);
}
__device__ __forceinline__ unsigned short f2bf(float f) {   // round-to-nearest-even
    unsigned int u = __float_as_uint(f);
    u += 0x7FFFu + ((u >> 16) & 1u);
    return (unsigned short)(u >> 16);
}

// merged independent setup: [0,CB) cast x->bf16 | [CB,CB+256) cast W ->
// transposed bf16 Wt | [CB+256, ...) per-chunk bucket histogram.
__global__ __launch_bounds__(256) void setup_all(
        const float4* __restrict__ x4, ushort4* __restrict__ hb, int n4, int CB,
        const float* __restrict__ W, unsigned short* __restrict__ Wt,
        const int* __restrict__ ec, int E, int* __restrict__ bucketCnt) {
    __shared__ int h[256];
    const int t = threadIdx.x;
    const int b = blockIdx.x;
    if (b < CB) {
        int i = b * 256 + t;
        if (i < n4) {
            float4 v = x4[i];
            ushort4 o;
            o.x = f2bf(v.x); o.y = f2bf(v.y); o.z = f2bf(v.z); o.w = f2bf(v.w);
            hb[i] = o;
        }
    } else if (b < CB + 256) {
        int idx = (b - CB) * 256 + t;      // 4*128*128 = 65536 elems
        int i = idx >> 14;
        int rem = idx & 16383;
        int k = rem >> 7, c = rem & 127;
        Wt[(i << 14) + c * 128 + k] = f2bf(W[idx]);
    } else {
        h[t] = 0;
        __syncthreads();
        const int e0 = (b - CB - 256) * CHUNK;
        const int cnt = min(CHUNK, E - e0);
        for (int i = t; i < cnt; i += 256) atomicAdd(&h[ec[e0 + i] >> BSH], 1);
        __syncthreads();
        if (h[t]) atomicAdd(&bucketCnt[t], h[t]);
    }
}

// exclusive scan over 256 bucket counts -> bucketBase, globCursor
__global__ __launch_bounds__(256) void bucket_scan(const int* __restrict__ bucketCnt,
                                                   int* __restrict__ bucketBase,
                                                   int* __restrict__ globCursor) {
    __shared__ int s[256];
    const int t = threadIdx.x;
    int v = bucketCnt[t];
    s[t] = v; __syncthreads();
    for (int off = 1; off < 256; off <<= 1) {
        int x = (t >= off) ? s[t - off] : 0;
        __syncthreads();
        s[t] += x;
        __syncthreads();
    }
    int excl = s[t] - v;
    bucketBase[t] = excl;
    globCursor[t] = excl;
}

// scatter (r,c) pairs into bucket-grouped array, LDS-staged & coalesced
__global__ __launch_bounds__(256) void scatter_pairs(const int* __restrict__ er,
                                                     const int* __restrict__ ec, int E,
                                                     int* __restrict__ globCursor,
                                                     int2* __restrict__ pairs) {
    __shared__ int h[256], lbase[256], cur[256], segd[256], s[256];
    __shared__ int2 stage[CHUNK];
    const int t = threadIdx.x;
    const int e0 = blockIdx.x * CHUNK;
    const int cnt = min(CHUNK, E - e0);

    h[t] = 0;
    __syncthreads();
    for (int i = t; i < cnt; i += 256) atomicAdd(&h[ec[e0 + i] >> BSH], 1);
    __syncthreads();
    int v = h[t];
    s[t] = v; __syncthreads();
    for (int off = 1; off < 256; off <<= 1) {
        int x = (t >= off) ? s[t - off] : 0;
        __syncthreads();
        s[t] += x;
        __syncthreads();
    }
    lbase[t] = s[t] - v;
    cur[t] = s[t] - v;
    segd[t] = atomicAdd(&globCursor[t], v) - lbase[t];
    __syncthreads();
    for (int i = t; i < cnt; i += 256) {
        int c = ec[e0 + i];
        int b = c >> BSH;
        int p = atomicAdd(&cur[b], 1);
        stage[p] = make_int2(er[e0 + i], c);
    }
    __syncthreads();
    for (int i = t; i < cnt; i += 256) {
        int2 pr = stage[i];
        int b = pr.y >> BSH;
        pairs[segd[b] + i] = pr;
    }
}

// one block per bucket. LDS hist+scan -> rowptr, dinv, slot fill.
// Also scales the bf16 x-cast (Hb0) rows of this bucket by dinv in place
// (S = dinv * x), so every layer uses the pre-scaled gather path.
__global__ __launch_bounds__(256) void fill_csr(const int2* __restrict__ pairs,
                                                const int* __restrict__ bucketBase,
                                                const int* __restrict__ bucketCnt,
                                                int N, int E, int NBUCK,
                                                int* __restrict__ rowptr,
                                                float* __restrict__ dinv,
                                                int* __restrict__ srcs,
                                                unsigned short* __restrict__ Hb0) {
    __shared__ int hist[512], lofs[512], s[256];
    const int t = threadIdx.x;
    const int b = blockIdx.x;
    const int c0 = b << BSH;
    const int base = bucketBase[b];
    const int cnt = bucketCnt[b];
    const int2* pp = pairs + base;

    hist[t] = 0; hist[t + 256] = 0;
    __syncthreads();
    for (int i = t; i < cnt; i += 256) atomicAdd(&hist[pp[i].y - c0], 1);
    __syncthreads();
    int a0 = hist[2 * t], a1 = hist[2 * t + 1];
    s[t] = a0 + a1; __syncthreads();
    for (int off = 1; off < 256; off <<= 1) {
        int x = (t >= off) ? s[t - off] : 0;
        __syncthreads();
        s[t] += x;
        __syncthreads();
    }
    int excl = s[t] - (a0 + a1);
    lofs[2 * t] = excl;
    lofs[2 * t + 1] = excl + a0;
    __syncthreads();
    const int nn = min(512, N - c0);
    for (int i = t; i < nn; i += 256) {
        rowptr[c0 + i] = base + lofs[i];
        dinv[c0 + i] = rsqrtf((float)hist[i] + 1.0f);
    }
    if (b == NBUCK - 1 && t == 0) rowptr[N] = E;
    __syncthreads();
    for (int i = t; i < cnt; i += 256) {
        int2 pr = pp[i];
        int p = atomicAdd(&lofs[pr.y - c0], 1);
        srcs[base + p] = pr.x;
    }
    // ---- scale Hb0 rows of this bucket by dinv (S = dinv * x) ----
    unsigned int* Hrow = (unsigned int*)Hb0 + (size_t)c0 * 64;   // 64 dwords/row
    for (int i = t; i < nn * 64; i += 256) {
        int r = i >> 6;
        float dv = rsqrtf((float)hist[r] + 1.0f);
        unsigned int v = Hrow[i];
        unsigned short lo = f2bf(bf2f((unsigned short)(v & 0xFFFFu)) * dv);
        unsigned short hi = f2bf(bf2f((unsigned short)(v >> 16)) * dv);
        Hrow[i] = ((unsigned int)hi << 16) | lo;
    }
}

// ---------------------------------------------------------------------------
// Fused layer: ONE WAVE per block, 16 target rows.
// Phase A (depth-2 pipelined): 4 sixteen-lane groups; group `quad` owns rows
//   quad*4..+3, one at a time; lane owns one 16B chunk of the 256B row.
//   Per batch iteration: compute next indices (waits srcs(b+1), issued
//   before h(b)) -> issue srcs(b+2) -> issue h(b+1) -> consume h(b).
//   Final batch masked: index clamped to self row, weight from rem count.
//   Inputs pre-scaled S = dinv*h -> no per-edge dinv anywhere.
//   Result P = dinv[row]*(sum S[src] + S[row]) -> bf16 into xor-swizzled
//   LDS A-tile (pitch 128, chunk pos = gl ^ row).
// Phase B: 16x16 MFMA gemm; A-frags from LDS (conflict-free ds_read_b128),
//   W-frags from global (L2-hot). Epilogue folds bias+relu+output-dinv;
//   LDS reused as out tile (pitch OP) -> coalesced 16B stores.
//   Layer 4 (writeDots): head dot fused, no Hn write.
// C/D: col=lane&15, row=(lane>>4)*4+reg (verified mapping).
// ---------------------------------------------------------------------------
__global__ __launch_bounds__(64, 4) void layer_fused(
        const int* __restrict__ rowptr, const int* __restrict__ srcs,
        const float* __restrict__ dinv, const unsigned short* __restrict__ H,
        const unsigned short* __restrict__ Wt, const float* __restrict__ bias,
        unsigned short* __restrict__ Hn, float* __restrict__ dots,
        const float* __restrict__ Wl, int N, int writeDots) {
    __shared__ __align__(16) unsigned short U[16 * OP];   // 4.25 KB
    const int lane = threadIdx.x;        // 0..63
    const int row16 = lane & 15;
    const int quad = lane >> 4;
    const int r0 = blockIdx.x * 16;
    const bf16x8* H8 = (const bf16x8*)H;     // 16 chunks (16B) per row
    const int gl = row16;                    // chunk index this lane owns

    // ---- phase A: aggregate 16 rows into swizzled LDS A-tile ----
#pragma unroll 1
    for (int sstep = 0; sstep < 4; ++sstep) {
        const int rt = quad * 4 + sstep;     // local row 0..15
        const int row = r0 + rt;
        float acc[8] = {0.f, 0.f, 0.f, 0.f, 0.f, 0.f, 0.f, 0.f};
        float sn = 0.f;
        if (row < N) {
            sn = dinv[row];
            int j = rowptr[row];
            const int end = rowptr[row + 1];
            // self-loop term (pre-scaled)
            bf16x8 hv = H8[(size_t)row * 16 + gl];
#pragma unroll
            for (int k = 0; k < 8; ++k) acc[k] = bf2f((unsigned short)hv[k]);
            const int ne = end - j;
            const int nb = (ne + 7) >> 3;     // masked 8-edge batches
            if (nb > 0) {
                i32x4u sA0, sA1, sB0, sB1;
                {   // srcs(0); then srcs(1) issued BEFORE h(0)
                    const i32x4u* sp = (const i32x4u*)(srcs + j);
                    sA0 = sp[0]; sA1 = sp[1];
                }
                if (nb > 1) {
                    const i32x4u* sp = (const i32x4u*)(srcs + j + 8);
                    sB0 = sp[0]; sB1 = sp[1];
                }
                bf16x8 hc[8], hn[8];
#pragma unroll
                for (int t = 0; t < 8; ++t) {       // issue h(0)
                    int idx = (t < 4) ? sA0[t] : sA1[t - 4];
                    int rr = (t < ne) ? idx : row;
                    hc[t] = H8[(size_t)rr * 16 + gl];
                }
#pragma unroll 1
                for (int b = 0; b < nb; ++b) {
                    if (b + 1 < nb) {
                        const int remn = ne - (b + 1) * 8;
                        int rn[8];
#pragma unroll
                        for (int t = 0; t < 8; ++t) {   // waits srcs(b+1) only
                            int idx = (t < 4) ? sB0[t] : sB1[t - 4];
                            rn[t] = (t < remn) ? idx : row;
                        }
                        if (b + 2 < nb) {               // srcs(b+2) BEFORE h(b+1)
                            const i32x4u* sp = (const i32x4u*)(srcs + j + (b + 2) * 8);
                            sB0 = sp[0]; sB1 = sp[1];
                        }
#pragma unroll
                        for (int t = 0; t < 8; ++t)     // issue h(b+1)
                            hn[t] = H8[(size_t)rn[t] * 16 + gl];
                    }
                    // consume h(b); weight from remaining count (no stored w[])
                    const int rem = ne - b * 8;
#pragma unroll
                    for (int t = 0; t < 8; ++t) {
                        const float w = (t < rem) ? 1.f : 0.f;
#pragma unroll
                        for (int k = 0; k < 8; ++k)
                            acc[k] = fmaf(w, bf2f((unsigned short)hc[t][k]), acc[k]);
                    }
#pragma unroll
                    for (int t = 0; t < 8; ++t) hc[t] = hn[t];
                }
            }
        }
        // P row (bf16) -> swizzled A-tile; rows >= N become zeros (sn=0)
        bf16x8 o;
#pragma unroll
        for (int k = 0; k < 8; ++k) o[k] = (short)f2bf(sn * acc[k]);
        *(bf16x8*)(U + rt * 128 + ((gl ^ rt) << 3)) = o;
    }
    __syncthreads();   // 1-wave block: compiles to cnt drain, no stall

    // ---- phase B: A fragments, all 4 K-chunks ----
    bf16x8 a0[4];
#pragma unroll
    for (int kc = 0; kc < 4; ++kc) {
        const int ph = (kc * 4 + quad) ^ row16;
        a0[kc] = *(const bf16x8*)(U + row16 * 128 + ph * 8);
    }
    __syncthreads();   // U is now reused as the out tile (pitch OP)

    // dinv of output rows (pre-scale stored features); not needed for dots
    float dv[4];
    if (!writeDots) {
#pragma unroll
        for (int i = 0; i < 4; ++i) {
            int ra = r0 + quad * 4 + i;
            dv[i] = (ra < N) ? dinv[ra] : 0.f;
        }
    }

    float rd[4] = {0.f, 0.f, 0.f, 0.f};
#pragma unroll
    for (int ct = 0; ct < 8; ++ct) {
        const int col = ct * 16 + row16;
        const bf16x8* wc = (const bf16x8*)(Wt + (size_t)col * 128);
        f32x4 acc0 = {0.f, 0.f, 0.f, 0.f};
#pragma unroll
        for (int kc = 0; kc < 4; ++kc) {
            const bf16x8 wf = wc[kc * 4 + quad];
            acc0 = __builtin_amdgcn_mfma_f32_16x16x32_bf16(a0[kc], wf, acc0, 0, 0, 0);
        }
        const float bv = bias[col];
        if (writeDots) {
            const float wl = Wl[col];
#pragma unroll
            for (int i = 0; i < 4; ++i) rd[i] += fmaxf(acc0[i] + bv, 0.f) * wl;
        } else {
#pragma unroll
            for (int i = 0; i < 4; ++i)
                U[(quad * 4 + i) * OP + col] = f2bf(dv[i] * fmaxf(acc0[i] + bv, 0.f));
        }
    }

    if (writeDots) {
#pragma unroll
        for (int m = 1; m < 16; m <<= 1)
#pragma unroll
            for (int i = 0; i < 4; ++i) rd[i] += __shfl_xor(rd[i], m, 64);
        if (row16 == 0) {
#pragma unroll
            for (int i = 0; i < 4; ++i) dots[r0 + quad * 4 + i] = rd[i];
        }
    } else {
        __syncthreads();
        // coalesced readback + store: 256 16B chunks per tile, 4/lane
#pragma unroll
        for (int i = 0; i < 4; ++i) {
            int idx = i * 64 + lane;
            int row = idx >> 4, c8 = idx & 15;
            bf16x8 v = *(const bf16x8*)(U + row * OP + c8 * 8);
            *(bf16x8*)(Hn + (size_t)(r0 + row) * 128 + c8 * 8) = v;
        }
    }
}

// one block per graph: binary-search node range in sorted batch, mean, +bl
__global__ __launch_bounds__(256) void pool_graphs(const float* __restrict__ dots,
                                                   const int* __restrict__ batch, int N,
                                                   const float* __restrict__ bl,
                                                   float* __restrict__ out) {
    __shared__ int bounds[2];
    __shared__ float red[4];
    const int g = blockIdx.x;
    const int t = threadIdx.x;
    if (t < 2) {
        int key = g + t;             // lower_bound(batch, key)
        int lo = 0, hi = N;
        while (lo < hi) {
            int mid = (lo + hi) >> 1;
            if (batch[mid] < key) lo = mid + 1; else hi = mid;
        }
        bounds[t] = lo;
    }
    __syncthreads();
    const int lo = bounds[0], hi = bounds[1];
    float s = 0.f;
    for (int i = lo + t; i < hi; i += 256) s += dots[i];
#pragma unroll
    for (int off = 32; off > 0; off >>= 1) s += __shfl_down(s, off, 64);
    if ((t & 63) == 0) red[t >> 6] = s;
    __syncthreads();
    if (t == 0) {
        float tot = red[0] + red[1] + red[2] + red[3];
        int cnt = hi - lo;
        out[g] = tot / (float)(cnt > 0 ? cnt : 1) + bl[0];
    }
}

extern "C" void kernel_launch(void* const* d_in, const int* in_sizes, int n_in,
                              void* d_out, int out_size, void* d_ws, size_t ws_size,
                              hipStream_t stream) {
    const float* x     = (const float*)d_in[0];
    const int*   eidx  = (const int*)d_in[1];    // int32 (harness converts int64)
    const int*   batch = (const int*)d_in[2];
    const float* Ws    = (const float*)d_in[3];
    const float* bs    = (const float*)d_in[4];
    const float* Wl    = (const float*)d_in[5];
    const float* bl    = (const float*)d_in[6];
    (void)n_in; (void)out_size;

    const int N = in_sizes[0] / D;
    const int E = in_sizes[1] / 2;
    const int* er = eidx;       // sources
    const int* ec = eidx + E;   // targets
    const int NBUCK = (N + 511) >> BSH;          // 512-node buckets (<= 256)
    const int NCHUNK = (E + CHUNK - 1) / CHUNK;

    // ---- workspace carve ----
    const int Npad = (N + 127) & ~127;
    const size_t hBytes = (size_t)Npad * D * sizeof(unsigned short); // 25.6 MB bf16
    auto al = [](size_t v) { return (v + 255) & ~(size_t)255; };
    char* base = (char*)d_ws;
    size_t off = 0;

    unsigned short* Hb0 = (unsigned short*)base; off = al(hBytes);
    int* bucketCnt  = (int*)(base + off);
    int* globCursor = bucketCnt + 256;
    off = al(off + 512 * sizeof(int));
    int*   bucketBase = (int*)(base + off);  off = al(off + 256 * sizeof(int));
    float* dinv   = (float*)(base + off);    off = al(off + (size_t)Npad * sizeof(float));
    float* dots   = (float*)(base + off);    off = al(off + (size_t)Npad * sizeof(float));
    int*   rowptr = (int*)(base + off);      off = al(off + (size_t)(Npad + 64) * sizeof(int));
    int*   srcs   = (int*)(base + off);      off = al(off + (size_t)E * sizeof(int) + 64);
    unsigned short* Wt = (unsigned short*)(base + off);   off = al(off + 4 * 128 * 128 * sizeof(unsigned short));

    // second bf16 buffer: in ws if it fits, else reuse x's 51.2 MB input buffer
    // (Npad*256B <= N*512B, so the alias stays in-bounds). pairs aliases Hb1:
    // CSR build completes before layer-1 gemm writes Hb1 (same stream).
    const bool twoBuf = ws_size >= off + hBytes;
    unsigned short* Hb1 = twoBuf ? (unsigned short*)(base + off)
                                 : (unsigned short*)d_in[0];
    int2* pairs = (int2*)Hb1;
    unsigned short* hb[2] = { Hb0, Hb1 };

    // ---- setup: memset bucketCnt; merged cast_x | cast_W | histogram ----
    hipMemsetAsync(bucketCnt, 0, 256 * sizeof(int), stream);
    const int n4 = N * D / 4;
    const int CB = (n4 + 255) / 256;
    setup_all<<<CB + 256 + NCHUNK, 256, 0, stream>>>((const float4*)x, (ushort4*)Hb0,
                                                     n4, CB, Ws, Wt, ec, E, bucketCnt);

    // ---- binned CSR build (once; reused by all 4 layers) ----
    bucket_scan<<<1, 256, 0, stream>>>(bucketCnt, bucketBase, globCursor);
    scatter_pairs<<<NCHUNK, 256, 0, stream>>>(er, ec, E, globCursor, pairs);
    fill_csr<<<NBUCK, 256, 0, stream>>>(pairs, bucketBase, bucketCnt, N, E, NBUCK,
                                        rowptr, dinv, srcs, Hb0);

    // ---- 4 fused layers: aggregate -> LDS A-tile -> MFMA (-> head dot) ----
    for (int i = 0; i < 4; ++i) {
        const unsigned short* Hc = hb[i & 1];
        unsigned short* Hn = hb[(i + 1) & 1];
        layer_fused<<<Npad / 16, 64, 0, stream>>>(rowptr, srcs, dinv, Hc,
                                                  Wt + (size_t)i * D * D,
                                                  bs + (size_t)i * D, Hn, dots, Wl,
                                                  N, (i == 3) ? 1 : 0);
    }

    // ---- mean pool (+bl) over fused per-node dots ----
    pool_graphs<<<NGRAPH, 256, 0, stream>>>(dots, batch, N, bl, (float*)d_out);
}

// Round 6
// 486.013 us; speedup vs baseline: 1.2684x; 1.0553x over previous
//
#include <hip/hip_runtime.h>

// ---------------------------------------------------------------------------
// GCN forward, reassociated: per layer h = relu( (A_hat h) W + b ).
// R18: concurrency fix #2 + setup fix.
//  - R17 post-mortem: 1-wave blocks are capped by the per-CU WORKGROUP limit
//    (~16), not VGPR/LDS -> occupancy stuck at ~10.5 waves/CU and gather BW
//    at 2.95 TB/s (R12's standalone pull: 21 waves/CU -> 3.32 TB/s).
//    Fix: 4 waves per 256-thread block, ZERO barriers — each wave owns a
//    private 4.25 KB LDS tile and independently runs gather->MFMA->store
//    for its 16 rows. Within-wave LDS ordering needs only lgkmcnt (compiler-
//    inserted); no s_barrier -> no R13-style pipe drain.
//  - R15-17 regression fix: the dinv pre-scale of the x-cast ran inside
//    fill_csr (196 blocks, ~3 waves/CU) costing ~40-50 µs. Now a dedicated
//    scale_x kernel (6250 blocks, ~10 µs).
//  - Gather loop: R17's masked-batch loop (proven 97->78 µs win) kept as-is.
// All layers pre-scaled (S = dinv*h); epilogue folds bias+relu+output-dinv;
// layer 4 fuses the head dot. CSR build unchanged. pairs aliases Hb1.
// NOTE: harness delivers integer inputs as int32 (edge_index/batch: int*).
// ---------------------------------------------------------------------------

constexpr int D = 128;
constexpr int NGRAPH = 512;
constexpr int CHUNK = 4096;       // edges per scatter block
constexpr int BSH = 9;            // 512 nodes per bucket
constexpr int OP = 136;           // out-tile pitch (ushorts): 272B, 16B-aligned rows

typedef __attribute__((ext_vector_type(8))) short bf16x8;
typedef __attribute__((ext_vector_type(4))) float f32x4;
typedef int i32x4u __attribute__((ext_vector_type(4), aligned(4)));

__device__ __forceinline__ float bf2f(unsigned short b) {
    return __uint_as_float(((unsigned int)b) << 16);
}
__device__ __forceinline__ unsigned short f2bf(float f) {   // round-to-nearest-even
    unsigned int u = __float_as_uint(f);
    u += 0x7FFFu + ((u >> 16) & 1u);
    return (unsigned short)(u >> 16);
}

// merged independent setup: [0,CB) cast x->bf16 | [CB,CB+256) cast W ->
// transposed bf16 Wt | [CB+256, ...) per-chunk bucket histogram.
__global__ __launch_bounds__(256) void setup_all(
        const float4* __restrict__ x4, ushort4* __restrict__ hb, int n4, int CB,
        const float* __restrict__ W, unsigned short* __restrict__ Wt,
        const int* __restrict__ ec, int E, int* __restrict__ bucketCnt) {
    __shared__ int h[256];
    const int t = threadIdx.x;
    const int b = blockIdx.x;
    if (b < CB) {
        int i = b * 256 + t;
        if (i < n4) {
            float4 v = x4[i];
            ushort4 o;
            o.x = f2bf(v.x); o.y = f2bf(v.y); o.z = f2bf(v.z); o.w = f2bf(v.w);
            hb[i] = o;
        }
    } else if (b < CB + 256) {
        int idx = (b - CB) * 256 + t;      // 4*128*128 = 65536 elems
        int i = idx >> 14;
        int rem = idx & 16383;
        int k = rem >> 7, c = rem & 127;
        Wt[(i << 14) + c * 128 + k] = f2bf(W[idx]);
    } else {
        h[t] = 0;
        __syncthreads();
        const int e0 = (b - CB - 256) * CHUNK;
        const int cnt = min(CHUNK, E - e0);
        for (int i = t; i < cnt; i += 256) atomicAdd(&h[ec[e0 + i] >> BSH], 1);
        __syncthreads();
        if (h[t]) atomicAdd(&bucketCnt[t], h[t]);
    }
}

// exclusive scan over 256 bucket counts -> bucketBase, globCursor
__global__ __launch_bounds__(256) void bucket_scan(const int* __restrict__ bucketCnt,
                                                   int* __restrict__ bucketBase,
                                                   int* __restrict__ globCursor) {
    __shared__ int s[256];
    const int t = threadIdx.x;
    int v = bucketCnt[t];
    s[t] = v; __syncthreads();
    for (int off = 1; off < 256; off <<= 1) {
        int x = (t >= off) ? s[t - off] : 0;
        __syncthreads();
        s[t] += x;
        __syncthreads();
    }
    int excl = s[t] - v;
    bucketBase[t] = excl;
    globCursor[t] = excl;
}

// scatter (r,c) pairs into bucket-grouped array, LDS-staged & coalesced
__global__ __launch_bounds__(256) void scatter_pairs(const int* __restrict__ er,
                                                     const int* __restrict__ ec, int E,
                                                     int* __restrict__ globCursor,
                                                     int2* __restrict__ pairs) {
    __shared__ int h[256], lbase[256], cur[256], segd[256], s[256];
    __shared__ int2 stage[CHUNK];
    const int t = threadIdx.x;
    const int e0 = blockIdx.x * CHUNK;
    const int cnt = min(CHUNK, E - e0);

    h[t] = 0;
    __syncthreads();
    for (int i = t; i < cnt; i += 256) atomicAdd(&h[ec[e0 + i] >> BSH], 1);
    __syncthreads();
    int v = h[t];
    s[t] = v; __syncthreads();
    for (int off = 1; off < 256; off <<= 1) {
        int x = (t >= off) ? s[t - off] : 0;
        __syncthreads();
        s[t] += x;
        __syncthreads();
    }
    lbase[t] = s[t] - v;
    cur[t] = s[t] - v;
    segd[t] = atomicAdd(&globCursor[t], v) - lbase[t];
    __syncthreads();
    for (int i = t; i < cnt; i += 256) {
        int c = ec[e0 + i];
        int b = c >> BSH;
        int p = atomicAdd(&cur[b], 1);
        stage[p] = make_int2(er[e0 + i], c);
    }
    __syncthreads();
    for (int i = t; i < cnt; i += 256) {
        int2 pr = stage[i];
        int b = pr.y >> BSH;
        pairs[segd[b] + i] = pr;
    }
}

// one block per bucket. LDS hist+scan -> rowptr, dinv, slot fill.
__global__ __launch_bounds__(256) void fill_csr(const int2* __restrict__ pairs,
                                                const int* __restrict__ bucketBase,
                                                const int* __restrict__ bucketCnt,
                                                int N, int E, int NBUCK,
                                                int* __restrict__ rowptr,
                                                float* __restrict__ dinv,
                                                int* __restrict__ srcs) {
    __shared__ int hist[512], lofs[512], s[256];
    const int t = threadIdx.x;
    const int b = blockIdx.x;
    const int c0 = b << BSH;
    const int base = bucketBase[b];
    const int cnt = bucketCnt[b];
    const int2* pp = pairs + base;

    hist[t] = 0; hist[t + 256] = 0;
    __syncthreads();
    for (int i = t; i < cnt; i += 256) atomicAdd(&hist[pp[i].y - c0], 1);
    __syncthreads();
    int a0 = hist[2 * t], a1 = hist[2 * t + 1];
    s[t] = a0 + a1; __syncthreads();
    for (int off = 1; off < 256; off <<= 1) {
        int x = (t >= off) ? s[t - off] : 0;
        __syncthreads();
        s[t] += x;
        __syncthreads();
    }
    int excl = s[t] - (a0 + a1);
    lofs[2 * t] = excl;
    lofs[2 * t + 1] = excl + a0;
    __syncthreads();
    const int nn = min(512, N - c0);
    for (int i = t; i < nn; i += 256) {
        rowptr[c0 + i] = base + lofs[i];
        dinv[c0 + i] = rsqrtf((float)hist[i] + 1.0f);
    }
    if (b == NBUCK - 1 && t == 0) rowptr[N] = E;
    __syncthreads();
    for (int i = t; i < cnt; i += 256) {
        int2 pr = pp[i];
        int p = atomicAdd(&lofs[pr.y - c0], 1);
        srcs[base + p] = pr.x;
    }
}

// scale the bf16 x-cast by dinv in place (S = dinv * x), properly sized:
// one uint4 (8 bf16) per thread, 16 uint4 per row.
__global__ __launch_bounds__(256) void scale_x(uint4* __restrict__ Hb0,
                                               const float* __restrict__ dinv,
                                               int nq) {                // nq = N*16
    int i = blockIdx.x * 256 + threadIdx.x;
    if (i >= nq) return;
    float dv = dinv[i >> 4];
    uint4 v = Hb0[i];
    unsigned int* p = (unsigned int*)&v;
#pragma unroll
    for (int k = 0; k < 4; ++k) {
        unsigned int d = p[k];
        unsigned short lo = f2bf(bf2f((unsigned short)(d & 0xFFFFu)) * dv);
        unsigned short hi = f2bf(bf2f((unsigned short)(d >> 16)) * dv);
        p[k] = ((unsigned int)hi << 16) | lo;
    }
    Hb0[i] = v;
}

// ---------------------------------------------------------------------------
// Fused layer: 256-thread block = 4 INDEPENDENT waves, each owning 16 rows
// and a private 4.25 KB LDS tile. NO barriers anywhere — within-wave LDS
// dependencies are ordered by lgkmcnt (compiler-inserted). 4-wave blocks
// escape the per-CU workgroup-count cap that limited 1-wave blocks to ~10
// waves/CU (R17).
// Phase A (per wave): 4 sixteen-lane groups; group `quad` owns 4 rows, one
//   at a time; lane owns one 16B chunk of the 256B row. Masked 8-edge
//   batches (index clamped to self, weight from remaining count) — R17's
//   proven loop. Inputs pre-scaled S = dinv*h -> no per-edge dinv.
//   P = dinv[row]*(sum S[src] + S[row]) -> bf16 into xor-swizzled A-tile.
// Phase B (per wave): 16x16 MFMA; A-frags from LDS (conflict-free
//   ds_read_b128), W-frags from global (L2-hot). Epilogue folds bias+relu+
//   output-dinv; LDS tile reused as out tile (pitch OP) -> coalesced 16B
//   stores. Layer 4 (writeDots): head dot fused, no Hn write.
// C/D: col=lane&15, row=(lane>>4)*4+reg (verified mapping).
// ---------------------------------------------------------------------------
__global__ __launch_bounds__(256, 4) void layer_fused(
        const int* __restrict__ rowptr, const int* __restrict__ srcs,
        const float* __restrict__ dinv, const unsigned short* __restrict__ H,
        const unsigned short* __restrict__ Wt, const float* __restrict__ bias,
        unsigned short* __restrict__ Hn, float* __restrict__ dots,
        const float* __restrict__ Wl, int N, int writeDots) {
    __shared__ __align__(16) unsigned short u[4][16 * OP];   // 17 KB, wave-private
    const int wave = threadIdx.x >> 6;
    const int lane = threadIdx.x & 63;
    const int row16 = lane & 15;
    const int quad = lane >> 4;
    const int r0 = blockIdx.x * 64 + wave * 16;
    unsigned short* U = u[wave];
    const bf16x8* H8 = (const bf16x8*)H;     // 16 chunks (16B) per row
    const int gl = row16;                    // chunk index this lane owns

    // ---- phase A: aggregate 16 rows into swizzled LDS A-tile ----
#pragma unroll 1
    for (int sstep = 0; sstep < 4; ++sstep) {
        const int rt = quad * 4 + sstep;     // local row 0..15
        const int row = r0 + rt;
        float acc[8] = {0.f, 0.f, 0.f, 0.f, 0.f, 0.f, 0.f, 0.f};
        float sn = 0.f;
        if (row < N) {
            sn = dinv[row];
            int j = rowptr[row];
            const int end = rowptr[row + 1];
            // self-loop term (pre-scaled)
            bf16x8 hv = H8[(size_t)row * 16 + gl];
#pragma unroll
            for (int k = 0; k < 8; ++k) acc[k] = bf2f((unsigned short)hv[k]);
            const int ne = end - j;
            const int nb = (ne + 7) >> 3;     // masked 8-edge batches
            if (nb > 0) {
                i32x4u sA0, sA1, sB0, sB1;
                {   // srcs(0); then srcs(1) issued BEFORE h(0)
                    const i32x4u* sp = (const i32x4u*)(srcs + j);
                    sA0 = sp[0]; sA1 = sp[1];
                }
                if (nb > 1) {
                    const i32x4u* sp = (const i32x4u*)(srcs + j + 8);
                    sB0 = sp[0]; sB1 = sp[1];
                }
                bf16x8 hc[8], hn[8];
#pragma unroll
                for (int t = 0; t < 8; ++t) {       // issue h(0)
                    int idx = (t < 4) ? sA0[t] : sA1[t - 4];
                    int rr = (t < ne) ? idx : row;
                    hc[t] = H8[(size_t)rr * 16 + gl];
                }
#pragma unroll 1
                for (int b = 0; b < nb; ++b) {
                    if (b + 1 < nb) {
                        const int remn = ne - (b + 1) * 8;
                        int rn[8];
#pragma unroll
                        for (int t = 0; t < 8; ++t) {   // waits srcs(b+1) only
                            int idx = (t < 4) ? sB0[t] : sB1[t - 4];
                            rn[t] = (t < remn) ? idx : row;
                        }
                        if (b + 2 < nb) {               // srcs(b+2) BEFORE h(b+1)
                            const i32x4u* sp = (const i32x4u*)(srcs + j + (b + 2) * 8);
                            sB0 = sp[0]; sB1 = sp[1];
                        }
#pragma unroll
                        for (int t = 0; t < 8; ++t)     // issue h(b+1)
                            hn[t] = H8[(size_t)rn[t] * 16 + gl];
                    }
                    // consume h(b); weight from remaining count (no stored w[])
                    const int rem = ne - b * 8;
#pragma unroll
                    for (int t = 0; t < 8; ++t) {
                        const float w = (t < rem) ? 1.f : 0.f;
#pragma unroll
                        for (int k = 0; k < 8; ++k)
                            acc[k] = fmaf(w, bf2f((unsigned short)hc[t][k]), acc[k]);
                    }
#pragma unroll
                    for (int t = 0; t < 8; ++t) hc[t] = hn[t];
                }
            }
        }
        // P row (bf16) -> swizzled A-tile; rows >= N become zeros (sn=0)
        bf16x8 o;
#pragma unroll
        for (int k = 0; k < 8; ++k) o[k] = (short)f2bf(sn * acc[k]);
        *(bf16x8*)(U + rt * 128 + ((gl ^ rt) << 3)) = o;
    }
    // no barrier: wave-private tile; lgkmcnt orders write->read within wave

    // ---- phase B: A fragments, all 4 K-chunks ----
    bf16x8 a0[4];
#pragma unroll
    for (int kc = 0; kc < 4; ++kc) {
        const int ph = (kc * 4 + quad) ^ row16;
        a0[kc] = *(const bf16x8*)(U + row16 * 128 + ph * 8);
    }
    // U is now reused as the out tile (pitch OP); same-wave aliasing ordered

    // dinv of output rows (pre-scale stored features); not needed for dots
    float dv[4];
    if (!writeDots) {
#pragma unroll
        for (int i = 0; i < 4; ++i) {
            int ra = r0 + quad * 4 + i;
            dv[i] = (ra < N) ? dinv[ra] : 0.f;
        }
    }

    float rd[4] = {0.f, 0.f, 0.f, 0.f};
#pragma unroll
    for (int ct = 0; ct < 8; ++ct) {
        const int col = ct * 16 + row16;
        const bf16x8* wc = (const bf16x8*)(Wt + (size_t)col * 128);
        f32x4 acc0 = {0.f, 0.f, 0.f, 0.f};
#pragma unroll
        for (int kc = 0; kc < 4; ++kc) {
            const bf16x8 wf = wc[kc * 4 + quad];
            acc0 = __builtin_amdgcn_mfma_f32_16x16x32_bf16(a0[kc], wf, acc0, 0, 0, 0);
        }
        const float bv = bias[col];
        if (writeDots) {
            const float wl = Wl[col];
#pragma unroll
            for (int i = 0; i < 4; ++i) rd[i] += fmaxf(acc0[i] + bv, 0.f) * wl;
        } else {
#pragma unroll
            for (int i = 0; i < 4; ++i)
                U[(quad * 4 + i) * OP + col] = f2bf(dv[i] * fmaxf(acc0[i] + bv, 0.f));
        }
    }

    if (writeDots) {
#pragma unroll
        for (int m = 1; m < 16; m <<= 1)
#pragma unroll
            for (int i = 0; i < 4; ++i) rd[i] += __shfl_xor(rd[i], m, 64);
        if (row16 == 0) {
#pragma unroll
            for (int i = 0; i < 4; ++i) dots[r0 + quad * 4 + i] = rd[i];
        }
    } else {
        // coalesced readback + store: 256 16B chunks per wave tile, 4/lane
#pragma unroll
        for (int i = 0; i < 4; ++i) {
            int idx = i * 64 + lane;
            int row = idx >> 4, c8 = idx & 15;
            bf16x8 v = *(const bf16x8*)(U + row * OP + c8 * 8);
            *(bf16x8*)(Hn + (size_t)(r0 + row) * 128 + c8 * 8) = v;
        }
    }
}

// one block per graph: binary-search node range in sorted batch, mean, +bl
__global__ __launch_bounds__(256) void pool_graphs(const float* __restrict__ dots,
                                                   const int* __restrict__ batch, int N,
                                                   const float* __restrict__ bl,
                                                   float* __restrict__ out) {
    __shared__ int bounds[2];
    __shared__ float red[4];
    const int g = blockIdx.x;
    const int t = threadIdx.x;
    if (t < 2) {
        int key = g + t;             // lower_bound(batch, key)
        int lo = 0, hi = N;
        while (lo < hi) {
            int mid = (lo + hi) >> 1;
            if (batch[mid] < key) lo = mid + 1; else hi = mid;
        }
        bounds[t] = lo;
    }
    __syncthreads();
    const int lo = bounds[0], hi = bounds[1];
    float s = 0.f;
    for (int i = lo + t; i < hi; i += 256) s += dots[i];
#pragma unroll
    for (int off = 32; off > 0; off >>= 1) s += __shfl_down(s, off, 64);
    if ((t & 63) == 0) red[t >> 6] = s;
    __syncthreads();
    if (t == 0) {
        float tot = red[0] + red[1] + red[2] + red[3];
        int cnt = hi - lo;
        out[g] = tot / (float)(cnt > 0 ? cnt : 1) + bl[0];
    }
}

extern "C" void kernel_launch(void* const* d_in, const int* in_sizes, int n_in,
                              void* d_out, int out_size, void* d_ws, size_t ws_size,
                              hipStream_t stream) {
    const float* x     = (const float*)d_in[0];
    const int*   eidx  = (const int*)d_in[1];    // int32 (harness converts int64)
    const int*   batch = (const int*)d_in[2];
    const float* Ws    = (const float*)d_in[3];
    const float* bs    = (const float*)d_in[4];
    const float* Wl    = (const float*)d_in[5];
    const float* bl    = (const float*)d_in[6];
    (void)n_in; (void)out_size;

    const int N = in_sizes[0] / D;
    const int E = in_sizes[1] / 2;
    const int* er = eidx;       // sources
    const int* ec = eidx + E;   // targets
    const int NBUCK = (N + 511) >> BSH;          // 512-node buckets (<= 256)
    const int NCHUNK = (E + CHUNK - 1) / CHUNK;

    // ---- workspace carve ----
    const int Npad = (N + 127) & ~127;
    const size_t hBytes = (size_t)Npad * D * sizeof(unsigned short); // 25.6 MB bf16
    auto al = [](size_t v) { return (v + 255) & ~(size_t)255; };
    char* base = (char*)d_ws;
    size_t off = 0;

    unsigned short* Hb0 = (unsigned short*)base; off = al(hBytes);
    int* bucketCnt  = (int*)(base + off);
    int* globCursor = bucketCnt + 256;
    off = al(off + 512 * sizeof(int));
    int*   bucketBase = (int*)(base + off);  off = al(off + 256 * sizeof(int));
    float* dinv   = (float*)(base + off);    off = al(off + (size_t)Npad * sizeof(float));
    float* dots   = (float*)(base + off);    off = al(off + (size_t)Npad * sizeof(float));
    int*   rowptr = (int*)(base + off);      off = al(off + (size_t)(Npad + 64) * sizeof(int));
    int*   srcs   = (int*)(base + off);      off = al(off + (size_t)E * sizeof(int) + 64);
    unsigned short* Wt = (unsigned short*)(base + off);   off = al(off + 4 * 128 * 128 * sizeof(unsigned short));

    // second bf16 buffer: in ws if it fits, else reuse x's 51.2 MB input buffer
    // (Npad*256B <= N*512B, so the alias stays in-bounds). pairs aliases Hb1:
    // CSR build completes before layer-1 gemm writes Hb1 (same stream).
    const bool twoBuf = ws_size >= off + hBytes;
    unsigned short* Hb1 = twoBuf ? (unsigned short*)(base + off)
                                 : (unsigned short*)d_in[0];
    int2* pairs = (int2*)Hb1;
    unsigned short* hb[2] = { Hb0, Hb1 };

    // ---- setup: memset bucketCnt; merged cast_x | cast_W | histogram ----
    hipMemsetAsync(bucketCnt, 0, 256 * sizeof(int), stream);
    const int n4 = N * D / 4;
    const int CB = (n4 + 255) / 256;
    setup_all<<<CB + 256 + NCHUNK, 256, 0, stream>>>((const float4*)x, (ushort4*)Hb0,
                                                     n4, CB, Ws, Wt, ec, E, bucketCnt);

    // ---- binned CSR build (once; reused by all 4 layers) ----
    bucket_scan<<<1, 256, 0, stream>>>(bucketCnt, bucketBase, globCursor);
    scatter_pairs<<<NCHUNK, 256, 0, stream>>>(er, ec, E, globCursor, pairs);
    fill_csr<<<NBUCK, 256, 0, stream>>>(pairs, bucketBase, bucketCnt, N, E, NBUCK,
                                        rowptr, dinv, srcs);
    // ---- pre-scale x-cast by dinv (S = dinv*x), properly-sized kernel ----
    const int nq = N * 16;                       // uint4 per row = 16
    scale_x<<<(nq + 255) / 256, 256, 0, stream>>>((uint4*)Hb0, dinv, nq);

    // ---- 4 fused layers: aggregate -> LDS A-tile -> MFMA (-> head dot) ----
    for (int i = 0; i < 4; ++i) {
        const unsigned short* Hc = hb[i & 1];
        unsigned short* Hn = hb[(i + 1) & 1];
        layer_fused<<<Npad / 64, 256, 0, stream>>>(rowptr, srcs, dinv, Hc,
                                                   Wt + (size_t)i * D * D,
                                                   bs + (size_t)i * D, Hn, dots, Wl,
                                                   N, (i == 3) ? 1 : 0);
    }

    // ---- mean pool (+bl) over fused per-node dots ----
    pool_graphs<<<NGRAPH, 256, 0, stream>>>(dots, batch, N, bl, (float*)d_out);
}